// Round 12
// baseline (238.173 us; speedup 1.0000x reference)
//
#include <hip/hip_runtime.h>
#include <math.h>

// Problem constants
#define BATCH 256
#define IC    1152
#define EDIM  8
#define NC    10
#define DV    16

#define KS    32                    // k-split factor (slabs)
#define ITK   36                    // i's per wsum block (K-chunk = 288)
#define IPP   12                    // i's per B-build piece (96 k)
#define SLABSTRIDE (NC * DV * BATCH) // 40960 floats per slab

typedef __attribute__((ext_vector_type(8))) __bf16 bf16x8;
typedef __attribute__((ext_vector_type(8))) short short8;
typedef __attribute__((ext_vector_type(4))) float f32x4;

__device__ __forceinline__ short f2bf(float f) {   // fp32 -> bf16 bits, RNE
    unsigned u = __float_as_uint(f);
    return (short)((u + 0x7FFF + ((u >> 16) & 1)) >> 16);
}

__device__ __forceinline__ float dot8w(float4 w0, float4 w1, float4 a, float4 b) {
    float u = w0.x * a.x;
    u = fmaf(w0.y, a.y, u); u = fmaf(w0.z, a.z, u); u = fmaf(w0.w, a.w, u);
    u = fmaf(w1.x, b.x, u); u = fmaf(w1.y, b.y, u);
    u = fmaf(w1.z, b.z, u); u = fmaf(w1.w, b.w, u);
    return u;
}

// ---------------------------------------------------------------------------
// One-time W reorder to MFMA A-fragment order, bf16:
// Wb2[c][kstep=k/32][lane=quad*16+d][j=e] where k = i*8+e, quad = i%4,
// kstep = i/4. A-load becomes one coalesced short8 per lane.
// ---------------------------------------------------------------------------
__global__ __launch_bounds__(256)
void caps_prepw(const float* __restrict__ W, short* __restrict__ Wb2)
{
    const int c = blockIdx.x;
    const int d = blockIdx.y;
    for (int i = threadIdx.x; i < IC; i += 256) {
        const float4 w0 = ((const float4*)W)[(((size_t)i * NC + c) * DV + d) * 2 + 0];
        const float4 w1 = ((const float4*)W)[(((size_t)i * NC + c) * DV + d) * 2 + 1];
        short8 s;
        s[0] = f2bf(w0.x); s[1] = f2bf(w0.y); s[2] = f2bf(w0.z); s[3] = f2bf(w0.w);
        s[4] = f2bf(w1.x); s[5] = f2bf(w1.y); s[6] = f2bf(w1.z); s[7] = f2bf(w1.w);
        *(short8*)&Wb2[((((size_t)c * 288 + (i >> 2)) * 64) + (i & 3) * 16 + d) * 8] = s;
    }
}

// ---------------------------------------------------------------------------
// x transpose: x[b][i][e] -> xT[i][b][e]  (+ one-time cw1 = softmax(bias))
// ---------------------------------------------------------------------------
__global__ __launch_bounds__(256)
void caps_xT(const float* __restrict__ x, const float* __restrict__ bias,
             float* __restrict__ xT, float* __restrict__ cw1)
{
    __shared__ float tile[16][132];
    const int t  = threadIdx.x;
    const int i0 = blockIdx.x * 16;
    const int b0 = blockIdx.y * 16;
    {
        const int b = t >> 4, i = t & 15;
        const float4* src = (const float4*)&x[((size_t)(b0 + b) * IC + i0 + i) * EDIM];
        float4 v0 = src[0], v1 = src[1];
        ((float4*)&tile[b][i * 8])[0] = v0;
        ((float4*)&tile[b][i * 8])[1] = v1;
    }
    if (blockIdx.y == 0 && t < 16 * NC) {
        const int i = i0 + t / NC;
        const int c = t - (t / NC) * NC;
        float ssum = 0.f, ec = 0.f;
        #pragma unroll
        for (int cc = 0; cc < NC; ++cc) {
            float e = __expf(bias[i * NC + cc]);
            ssum += e;
            if (cc == c) ec = e;
        }
        cw1[i * NC + c] = ec / ssum;
    }
    __syncthreads();
    {
        const int i = t >> 4, b = t & 15;
        float4 v0 = ((const float4*)&tile[b][i * 8])[0];
        float4 v1 = ((const float4*)&tile[b][i * 8])[1];
        float4* dst = (float4*)&xT[((size_t)(i0 + i) * BATCH + b0 + b) * EDIM];
        dst[0] = v0;
        dst[1] = v1;
    }
}

// ---------------------------------------------------------------------------
// Kernel A: routing coefficients. Grid = 1152 (one i), block = 256 (lane = b).
// W read via uniform-address VECTOR loads (asm-opaqued offset defeats the
// s_load scalarizer): L1-resident 5 KB, vmcnt-pipelined — replaces R11's
// LDS broadcast (ds_read_b128 ~12 cyc per 4 W floats = the DS-pipe wall).
//   MODE 2: logits = (u.v1) + 2*bias
//   MODE 3: logits = (u.v2) + (u.v1) + 3*bias   (b2 never materialized)
// ---------------------------------------------------------------------------
template<int MODE>
__global__ __launch_bounds__(256)
void caps_cw(const float* __restrict__ xT,
             const float* __restrict__ W,
             const float* __restrict__ bias,
             const float* __restrict__ vT1,
             const float* __restrict__ vT2,
             float* __restrict__ cw_g)
{
    const int i = blockIdx.x;
    const int b = threadIdx.x;

    int voff = 0;
    asm volatile("" : "+v"(voff));   // opaque zero -> forces vector addressing
    const float4* Wg = (const float4*)(W + (size_t)i * NC * DV * EDIM);

    const float4 xv0 = ((const float4*)xT)[((size_t)i * BATCH + b) * 2 + 0];
    const float4 xv1 = ((const float4*)xT)[((size_t)i * BATCH + b) * 2 + 1];

    float t2[NC];
    float t3[NC];

    #pragma unroll
    for (int c = 0; c < NC; ++c) {
        float a2 = 0.f, a3 = 0.f;
        #pragma unroll
        for (int d = 0; d < DV; ++d) {
            float4 w0 = Wg[(c * DV + d) * 2 + 0 + voff];
            float4 w1 = Wg[(c * DV + d) * 2 + 1 + voff];
            float u = dot8w(w0, w1, xv0, xv1);
            a2 = fmaf(u, vT1[(c * DV + d) * BATCH + b], a2);
            if (MODE == 3)
                a3 = fmaf(u, vT2[(c * DV + d) * BATCH + b], a3);
        }
        t2[c] = a2;
        if (MODE == 3) t3[c] = a3;
    }

    float ex[NC];
    float ssum = 0.f;
    #pragma unroll
    for (int c = 0; c < NC; ++c) {
        float bv = bias[i * NC + c];
        float logit = (MODE == 2) ? (t2[c] + 2.0f * bv)
                                  : (t3[c] + t2[c] + 3.0f * bv);
        ex[c] = __expf(logit);
        ssum += ex[c];
    }
    float inv = 1.0f / ssum;
    #pragma unroll
    for (int c = 0; c < NC; ++c)
        cw_g[((size_t)i * NC + c) * BATCH + b] = ex[c] * inv;
}

// ---------------------------------------------------------------------------
// Kernel B (MFMA): s_c[d,b] = sum_k Wb_c[d,k] * (cw_c*x)[k,b], k=(i,e).
// Grid (32 ks, 10 c), block 256 = 4 waves. Per block: K-chunk 288 (36 i) in
// 3 pieces of 96 k: all threads build B bf16 tile in LDS (1 coalesced mul+cvt
// per element), then each wave runs 3 k-steps x 4 n-tiles of
// mfma_f32_16x16x32_bf16 (m=d, n=b). A-frags: one coalesced short8 from Wb2.
// B_lds row padded 96->104 shorts: 2-way banks only (free).
// ---------------------------------------------------------------------------
template<int FIRST>
__global__ __launch_bounds__(256)
void caps_wsum_mfma(const float* __restrict__ xT,
                    const short* __restrict__ Wb2,
                    const float* __restrict__ cw1,
                    const float* __restrict__ cw_g,
                    float* __restrict__ s_part)
{
    __shared__ short B_lds[BATCH][104];   // 53 KB

    const int ks   = blockIdx.x;          // 0..31
    const int c    = blockIdx.y;          // 0..9
    const int tid  = threadIdx.x;
    const int lane = tid & 63;
    const int w    = tid >> 6;
    const int i0   = ks * ITK;

    f32x4 acc[4];
    #pragma unroll
    for (int t = 0; t < 4; ++t) acc[t] = (f32x4){0.f, 0.f, 0.f, 0.f};

    const short8* Ag = (const short8*)Wb2;

    #pragma unroll 1
    for (int piece = 0; piece < 3; ++piece) {
        {   // ---- build B piece: 12 i x 8 e rows, 256 b cols ----
            const int b = tid;
            #pragma unroll
            for (int il = 0; il < IPP; ++il) {
                const int i = i0 + piece * IPP + il;
                float cwv = FIRST ? cw1[i * NC + c]
                                  : cw_g[((size_t)i * NC + c) * BATCH + b];
                const float4 x0 = ((const float4*)xT)[((size_t)i * BATCH + b) * 2 + 0];
                const float4 x1 = ((const float4*)xT)[((size_t)i * BATCH + b) * 2 + 1];
                short8 s;
                s[0] = f2bf(cwv * x0.x); s[1] = f2bf(cwv * x0.y);
                s[2] = f2bf(cwv * x0.z); s[3] = f2bf(cwv * x0.w);
                s[4] = f2bf(cwv * x1.x); s[5] = f2bf(cwv * x1.y);
                s[6] = f2bf(cwv * x1.z); s[7] = f2bf(cwv * x1.w);
                *(short8*)&B_lds[b][il * 8] = s;
            }
        }
        __syncthreads();
        // ---- MFMA: 3 k-steps of 32; 4 n-tiles (b) per wave ----
        #pragma unroll
        for (int kl = 0; kl < 3; ++kl) {
            const int kg = ks * 9 + piece * 3 + kl;       // global k-step
            short8 a8 = Ag[((size_t)c * 288 + kg) * 64 + lane];
            bf16x8 af = __builtin_bit_cast(bf16x8, a8);
            #pragma unroll
            for (int t = 0; t < 4; ++t) {
                const int brow = (w * 4 + t) * 16 + (lane & 15);
                short8 b8 = *(const short8*)&B_lds[brow][kl * 32 + (lane >> 4) * 8];
                bf16x8 bf = __builtin_bit_cast(bf16x8, b8);
                acc[t] = __builtin_amdgcn_mfma_f32_16x16x32_bf16(af, bf, acc[t], 0, 0, 0);
            }
        }
        __syncthreads();
    }

    // ---- epilogue: C layout col(n=b)=lane&15, row(m=d)=quad*4+reg ----
    #pragma unroll
    for (int t = 0; t < 4; ++t) {
        const int b = (w * 4 + t) * 16 + (lane & 15);
        #pragma unroll
        for (int r = 0; r < 4; ++r) {
            const int d = (lane >> 4) * 4 + r;
            s_part[(((size_t)ks * NC + c) * DV + d) * BATCH + b] = acc[t][r];
        }
    }
}

// ---------------------------------------------------------------------------
// Squash: reduce 32 slabs + squash. Grid = (10 c, 16 bgrp), block = 1024.
// LAST=0 -> vT[c][d][b]; LAST=1 -> out[b][c][d].
// ---------------------------------------------------------------------------
template<int LAST>
__global__ __launch_bounds__(1024)
void caps_squash(const float* __restrict__ s_part, float* __restrict__ outp)
{
    __shared__ float part[4][DV][17];
    const int c  = blockIdx.x;
    const int bg = blockIdx.y;
    const int bs = threadIdx.x & 15;
    const int d  = (threadIdx.x >> 4) & 15;
    const int sg = threadIdx.x >> 8;
    const int b  = bg * 16 + bs;

    float a0 = 0.f, a1 = 0.f;
    #pragma unroll
    for (int j = 0; j < 8; j += 2) {
        a0 += s_part[(((size_t)(sg * 8 + j + 0) * NC + c) * DV + d) * BATCH + b];
        a1 += s_part[(((size_t)(sg * 8 + j + 1) * NC + c) * DV + d) * BATCH + b];
    }
    part[sg][d][bs] = a0 + a1;
    __syncthreads();
    if (sg == 0)
        part[0][d][bs] = (part[0][d][bs] + part[1][d][bs])
                       + (part[2][d][bs] + part[3][d][bs]);
    __syncthreads();
    if (sg == 0) {
        float s = part[0][d][bs];
        float sq = 0.f;
        #pragma unroll
        for (int k = 0; k < DV; ++k) {
            float v = part[0][k][bs];
            sq = fmaf(v, v, sq);
        }
        // scale = sq/(1+sq)/sqrt(sq+EPS), EPS = 1e-7 (matches reference)
        float scale = sq / ((1.0f + sq) * sqrtf(sq + 1e-7f));
        float val = scale * s;
        if (LAST)
            outp[((size_t)b * NC + c) * DV + d] = val;   // out[b][c][d]
        else
            outp[(c * DV + d) * BATCH + b] = val;        // vT[c][d][b]
    }
}

// ---------------------------------------------------------------------------
extern "C" void kernel_launch(void* const* d_in, const int* in_sizes, int n_in,
                              void* d_out, int out_size, void* d_ws, size_t ws_size,
                              hipStream_t stream)
{
    const float* x    = (const float*)d_in[0];   // [256,1152,8]
    const float* W    = (const float*)d_in[1];   // [1152,10,16,8]
    const float* bias = (const float*)d_in[2];   // [1152,10]
    float* out = (float*)d_out;                  // [256,10,16]

    float* ws     = (float*)d_ws;
    float* s_part = ws;                                   // 32*40960 = 1,310,720 f
    float* cw_g   = s_part + (size_t)KS * SLABSTRIDE;     // 2,949,120 f
    float* vT1    = cw_g + (size_t)IC * NC * BATCH;       //    40,960 f
    float* vT2    = vT1 + NC * DV * BATCH;                //    40,960 f
    float* xT     = vT2 + NC * DV * BATCH;                // 2,359,296 f
    float* cw1    = xT + (size_t)IC * BATCH * EDIM;       //    11,520 f
    short* Wb2    = (short*)(cw1 + IC * NC);              // 1,474,560 sh (2.95 MB)
    // total ws use: ~29.8 MB (< 35.5 MB proven)

    dim3 gT(IC / 16, BATCH / 16);   // x transpose
    dim3 gP(NC, DV);                // W reorder
    dim3 gM(KS, NC);                // 320 MFMA blocks
    dim3 gS(NC, 16);                // squash

    // one-time preps (independent)
    caps_prepw<<<gP, 256, 0, stream>>>(W, Wb2);
    caps_xT<<<gT, 256, 0, stream>>>(x, bias, xT, cw1);
    // iter 1
    caps_wsum_mfma<1><<<gM, 256, 0, stream>>>(xT, Wb2, cw1, cw_g, s_part);
    caps_squash<0><<<gS, 1024, 0, stream>>>(s_part, vT1);
    // iter 2
    caps_cw<2><<<IC, 256, 0, stream>>>(xT, W, bias, vT1, vT1, cw_g);
    caps_wsum_mfma<0><<<gM, 256, 0, stream>>>(xT, Wb2, cw1, cw_g, s_part);
    caps_squash<0><<<gS, 1024, 0, stream>>>(s_part, vT2);
    // iter 3
    caps_cw<3><<<IC, 256, 0, stream>>>(xT, W, bias, vT1, vT2, cw_g);
    caps_wsum_mfma<0><<<gM, 256, 0, stream>>>(xT, Wb2, cw1, cw_g, s_part);
    caps_squash<1><<<gS, 1024, 0, stream>>>(s_part, out);
}